// Round 6
// baseline (220.531 us; speedup 1.0000x reference)
//
#include <hip/hip_runtime.h>

#define CH 128

typedef unsigned int uint;
typedef unsigned short ushort;
typedef __attribute__((ext_vector_type(8))) short bf16x8;
typedef __attribute__((ext_vector_type(4))) float f32x4;

__device__ inline ushort f2bf(float f) {
    uint u = __float_as_uint(f);
    u += 0x7fffu + ((u >> 16) & 1u);     // RNE
    return (ushort)(u >> 16);
}
__device__ inline float blo(uint v) { return __uint_as_float(v << 16); }
__device__ inline float bhi(uint v) { return __uint_as_float(v & 0xffff0000u); }
__device__ inline uint pk(float a, float b) { return (uint)f2bf(a) | ((uint)f2bf(b) << 16); }

// ---------------- merged: weight transpose-convert (blocks 0..127) + deg zero (rest) ----------------
__global__ void k_prolog(const float* __restrict__ W00, const float* __restrict__ W01,
                         const float* __restrict__ W10, const float* __restrict__ W11,
                         uint* __restrict__ Wt0, uint* __restrict__ Wt1,
                         int* __restrict__ deg, int N) {
    if (blockIdx.x < 128) {
        int tid = blockIdx.x * 256 + threadIdx.x;      // 0..32767
        int which = tid >> 14;
        int t = tid & 16383;
        int col = t & 127, kp = t >> 7;
        int k = kp * 2;
        const float* W = (which == 0) ? ((k < 128) ? W00 : W01) : ((k < 128) ? W10 : W11);
        uint* Wt = (which == 0) ? Wt0 : Wt1;
        int kk = k & 127;
        float f0 = W[(size_t)kk * 128 + col];
        float f1 = W[(size_t)(kk + 1) * 128 + col];
        Wt[(size_t)col * 128 + kp] = pk(f0, f1);
    } else {
        int i = (blockIdx.x - 128) * 256 + threadIdx.x;
        if (i < N) deg[i] = 0;
    }
}

// ---------------- degree + per-edge slot ----------------
__global__ void k_deg(const int* __restrict__ row, int* __restrict__ deg,
                      int* __restrict__ pos, int E) {
    int e = blockIdx.x * blockDim.x + threadIdx.x;
    if (e < E) pos[e] = atomicAdd(&deg[row[e]], 1);
}

// ---------------- x convert (+ inline dinv compute/store) ----------------
__global__ void k_cvt_x(const float4* __restrict__ X, const int* __restrict__ deg,
                        float* __restrict__ dinv,
                        uint2* __restrict__ Xb, uint2* __restrict__ Xsb, int n4) {
    int i = blockIdx.x * 256 + threadIdx.x;
    if (i >= n4) return;
    int node = i >> 5;
    int d = deg[node];
    float s = (d > 0) ? rsqrtf((float)d) : 0.0f;
    if ((i & 31) == 0) dinv[node] = s;
    float4 v = X[i];
    Xb[i]  = make_uint2(pk(v.x, v.y), pk(v.z, v.w));
    Xsb[i] = make_uint2(pk(v.x * s, v.y * s), pk(v.z * s, v.w * s));
}

// ---------------- rowStart: self-computed prefix base + in-block scan ----------------
__global__ void k_rowstart(const int* __restrict__ deg, int* __restrict__ rowStart, int N) {
    __shared__ int s[256];
    const int base0 = blockIdx.x * 256;
    int part = 0;
    for (int t = threadIdx.x; t < base0; t += 256) part += deg[t];
    s[threadIdx.x] = part;
    __syncthreads();
    for (int off = 128; off > 0; off >>= 1) {
        if (threadIdx.x < off) s[threadIdx.x] += s[threadIdx.x + off];
        __syncthreads();
    }
    const int base = s[0];
    __syncthreads();
    int i = base0 + threadIdx.x;
    int v = (i < N) ? deg[i] : 0;
    s[threadIdx.x] = v;
    __syncthreads();
    for (int off = 1; off < 256; off <<= 1) {
        int t = (threadIdx.x >= off) ? s[threadIdx.x - off] : 0;
        __syncthreads();
        s[threadIdx.x] += t;
        __syncthreads();
    }
    if (i < N) {
        int incl = s[threadIdx.x];
        rowStart[i] = base + incl - v;
        if (i == N - 1) rowStart[N] = base + incl;
    }
}

// ---------------- CSR fill: pure scatter, no atomics ----------------
__global__ void k_fill(const int* __restrict__ row, const int* __restrict__ col,
                       const int* __restrict__ rowStart, const int* __restrict__ pos,
                       int* __restrict__ csr, int E) {
    int e = blockIdx.x * blockDim.x + threadIdx.x;
    if (e < E) csr[rowStart[row[e]] + pos[e]] = col[e];
}

// ---------------- pass-sliced SpMM: Ob[i][slice] = bf16( -dinv[i] * sum_j Xs[j][slice] ) ----------
// Each pass covers 32 channels (16 uints = 64B per node) -> slice working set 2.56MB, L2-resident.
// 16 lanes per row (lane owns 1 uint = 2ch), unroll x4 -> 4 outstanding 64B gathers per row.
__global__ __launch_bounds__(256) void k_spmm_p(const uint* __restrict__ Xs,
                                                const float* __restrict__ dinv,
                                                const int* __restrict__ rowStart,
                                                const int* __restrict__ csr,
                                                uint* __restrict__ Ob, int N, int pass) {
    int r = (int)((blockIdx.x * 256 + threadIdx.x) >> 4);
    int l = threadIdx.x & 15;
    if (r >= N) return;
    int s = rowStart[r], e = rowStart[r + 1];
    const uint* X = Xs + (size_t)pass * 16 + l;
    float a0 = 0.f, a1 = 0.f;
    int k = s;
    for (; k + 4 <= e; k += 4) {
        int j0 = csr[k + 0], j1 = csr[k + 1], j2 = csr[k + 2], j3 = csr[k + 3];
        uint v0 = X[(size_t)j0 * 64];
        uint v1 = X[(size_t)j1 * 64];
        uint v2 = X[(size_t)j2 * 64];
        uint v3 = X[(size_t)j3 * 64];
        a0 += (blo(v0) + blo(v1)) + (blo(v2) + blo(v3));
        a1 += (bhi(v0) + bhi(v1)) + (bhi(v2) + bhi(v3));
    }
    for (; k < e; ++k) {
        uint v = X[(size_t)csr[k] * 64];
        a0 += blo(v); a1 += bhi(v);
    }
    float sc = -dinv[r];
    Ob[(size_t)r * 64 + pass * 16 + l] = pk(a0 * sc, a1 * sc);
}

// ---------------- MFMA GEMM: out = epi( [A1|A2] @ Wt^T + bias ) ----------------
__global__ __launch_bounds__(512) void k_gemm_mfma(const uint* __restrict__ A1,
                                                   const uint* __restrict__ A2,
                                                   const uint* __restrict__ Wt,
                                                   const float* __restrict__ bias,
                                                   const float* __restrict__ xres,
                                                   const float* __restrict__ dinv,
                                                   void* __restrict__ outp,
                                                   uint* __restrict__ outs,
                                                   int N, int mode) {
    __shared__ uint AsU[2][128 * 20];
    __shared__ uint WsU[2][128 * 20];

    const int tid = threadIdx.x;
    const int lane = tid & 63;
    const int wid = tid >> 6;
    const int wr = wid >> 1;
    const int wc = wid & 1;
    const int row0 = blockIdx.x * 128;
    const int l16 = lane & 15;
    const int lk = lane >> 4;

    f32x4 acc[2][4];
    #pragma unroll
    for (int m = 0; m < 2; m++)
        #pragma unroll
        for (int n = 0; n < 4; n++)
            acc[m][n] = (f32x4){0.f, 0.f, 0.f, 0.f};

    const int sr = tid >> 2;
    const int sc4 = tid & 3;
    const uint4* A1p = (const uint4*)A1;
    const uint4* A2p = (const uint4*)A2;
    const uint4* Wtp = (const uint4*)Wt;
    const int arow = min(row0 + sr, N - 1);

    uint4 ga, gw;
    ga = A1p[(size_t)arow * 16 + sc4];
    gw = Wtp[(size_t)sr * 32 + sc4];
    *(uint4*)&AsU[0][sr * 20 + sc4 * 4] = ga;
    *(uint4*)&WsU[0][sr * 20 + sc4 * 4] = gw;
    __syncthreads();

    for (int t = 0; t < 8; ++t) {
        const int cur = t & 1;
        if (t < 7) {
            const int k0 = (t + 1) * 32;
            const uint4* Ap = (k0 < 128) ? A1p : A2p;
            const int kk = k0 & 127;
            ga = Ap[(size_t)arow * 16 + (kk >> 3) + sc4];
            gw = Wtp[(size_t)sr * 32 + (k0 >> 3) + sc4];
        }

        bf16x8 bfr[4];
        #pragma unroll
        for (int n = 0; n < 4; n++) {
            int col = wc * 64 + n * 16 + l16;
            bfr[n] = *(const bf16x8*)&WsU[cur][col * 20 + lk * 4];
        }
        #pragma unroll
        for (int m = 0; m < 2; m++) {
            int row = wr * 32 + m * 16 + l16;
            bf16x8 afr = *(const bf16x8*)&AsU[cur][row * 20 + lk * 4];
            #pragma unroll
            for (int n = 0; n < 4; n++)
                acc[m][n] = __builtin_amdgcn_mfma_f32_16x16x32_bf16(afr, bfr[n], acc[m][n], 0, 0, 0);
        }

        if (t < 7) {
            *(uint4*)&AsU[cur ^ 1][sr * 20 + sc4 * 4] = ga;
            *(uint4*)&WsU[cur ^ 1][sr * 20 + sc4 * 4] = gw;
            __syncthreads();
        }
    }

    if (mode == 0) {
        ushort* O = (ushort*)outp;
        ushort* S = (ushort*)outs;
        #pragma unroll
        for (int m = 0; m < 2; m++) {
            #pragma unroll
            for (int r = 0; r < 4; r++) {
                int rg = row0 + wr * 32 + m * 16 + lk * 4 + r;
                if (rg >= N) continue;
                float sc = dinv[rg];
                #pragma unroll
                for (int n = 0; n < 4; n++) {
                    const int col = wc * 64 + n * 16 + l16;
                    float v = fmaxf(acc[m][n][r] + bias[col], 0.f);
                    O[(size_t)rg * 128 + col] = f2bf(v);
                    S[(size_t)rg * 128 + col] = f2bf(v * sc);
                }
            }
        }
    } else {
        float* O = (float*)outp;
        #pragma unroll
        for (int m = 0; m < 2; m++) {
            #pragma unroll
            for (int r = 0; r < 4; r++) {
                int rg = row0 + wr * 32 + m * 16 + lk * 4 + r;
                if (rg >= N) continue;
                #pragma unroll
                for (int n = 0; n < 4; n++) {
                    const int col = wc * 64 + n * 16 + l16;
                    float v = fmaxf(acc[m][n][r] + bias[col], 0.f);
                    O[(size_t)rg * 128 + col] = 0.5f * (v + xres[(size_t)rg * 128 + col]);
                }
            }
        }
    }
}

extern "C" void kernel_launch(void* const* d_in, const int* in_sizes, int n_in,
                              void* d_out, int out_size, void* d_ws, size_t ws_size,
                              hipStream_t stream) {
    const float* x   = (const float*)d_in[0];
    const int*   ei  = (const int*)d_in[1];
    const float* W00 = (const float*)d_in[2];
    const float* W01 = (const float*)d_in[3];
    const float* b0  = (const float*)d_in[4];
    const float* W10 = (const float*)d_in[5];
    const float* W11 = (const float*)d_in[6];
    const float* b1  = (const float*)d_in[7];
    float* out = (float*)d_out;

    const int N = in_sizes[0] / CH;   // 40000
    const int E = in_sizes[1] / 2;    // 640000
    const int* row = ei;
    const int* col = ei + E;

    char* ws = (char*)d_ws;
    size_t off = 0;
    auto alloc = [&](size_t bytes) -> void* {
        void* p = ws + off;
        off += (bytes + 255) & ~(size_t)255;
        return p;
    };
    int*   deg      = (int*)alloc((size_t)N * 4);
    float* dinv     = (float*)alloc((size_t)N * 4);
    int*   rowStart = (int*)alloc((size_t)(N + 1) * 4);
    int*   pos      = (int*)alloc((size_t)E * 4);
    int*   csr      = (int*)alloc((size_t)E * 4);
    uint*  xb       = (uint*)alloc((size_t)N * 64 * 4);
    uint*  xsb      = (uint*)alloc((size_t)N * 64 * 4);
    uint*  Lb       = (uint*)alloc((size_t)N * 64 * 4);
    uint*  yb       = (uint*)alloc((size_t)N * 64 * 4);
    uint*  ysb      = (uint*)alloc((size_t)N * 64 * 4);
    uint*  Wt0      = (uint*)alloc(128 * 128 * 4);
    uint*  Wt1      = (uint*)alloc(128 * 128 * 4);

    const int nB = (N + 255) / 256;   // 157

    k_prolog<<<128 + nB, 256, 0, stream>>>(W00, W01, W10, W11, Wt0, Wt1, deg, N);
    k_deg<<<(E + 255) / 256, 256, 0, stream>>>(row, deg, pos, E);
    k_cvt_x<<<(N * 32 + 255) / 256, 256, 0, stream>>>((const float4*)x, deg, dinv,
                                                      (uint2*)xb, (uint2*)xsb, N * 32);
    k_rowstart<<<nB, 256, 0, stream>>>(deg, rowStart, N);
    k_fill<<<(E + 255) / 256, 256, 0, stream>>>(row, col, rowStart, pos, csr, E);

    const int gemmBlocks = (N + 127) / 128;
    const int spmmBlocks = (N * 16 + 255) / 256;   // 2500

    // layer 1: 4 channel-sliced passes, each slice L2-resident
    for (int p = 0; p < 4; ++p)
        k_spmm_p<<<spmmBlocks, 256, 0, stream>>>(xsb, dinv, rowStart, csr, Lb, N, p);
    k_gemm_mfma<<<gemmBlocks, 512, 0, stream>>>(xb, Lb, Wt0, b0, nullptr, dinv,
                                                (void*)yb, ysb, N, 0);

    // layer 2
    for (int p = 0; p < 4; ++p)
        k_spmm_p<<<spmmBlocks, 256, 0, stream>>>(ysb, dinv, rowStart, csr, Lb, N, p);
    k_gemm_mfma<<<gemmBlocks, 512, 0, stream>>>(yb, Lb, Wt1, b1, x, dinv,
                                                (void*)out, nullptr, N, 1);
}

// Round 7
// 155.548 us; speedup vs baseline: 1.4178x; 1.4178x over previous
//
#include <hip/hip_runtime.h>

#define CH 128

typedef unsigned int uint;
typedef unsigned short ushort;
typedef __attribute__((ext_vector_type(8))) short bf16x8;
typedef __attribute__((ext_vector_type(4))) float f32x4;

__device__ inline ushort f2bf(float f) {
    uint u = __float_as_uint(f);
    u += 0x7fffu + ((u >> 16) & 1u);     // RNE
    return (ushort)(u >> 16);
}
__device__ inline float blo(uint v) { return __uint_as_float(v << 16); }
__device__ inline float bhi(uint v) { return __uint_as_float(v & 0xffff0000u); }
__device__ inline uint pk(float a, float b) { return (uint)f2bf(a) | ((uint)f2bf(b) << 16); }

// ---------------- merged: weight transpose-convert (blocks 0..127) + deg zero (rest) ----------------
__global__ void k_prolog(const float* __restrict__ W00, const float* __restrict__ W01,
                         const float* __restrict__ W10, const float* __restrict__ W11,
                         uint* __restrict__ Wt0, uint* __restrict__ Wt1,
                         int* __restrict__ deg, int N) {
    if (blockIdx.x < 128) {
        int tid = blockIdx.x * 256 + threadIdx.x;      // 0..32767
        int which = tid >> 14;
        int t = tid & 16383;
        int col = t & 127, kp = t >> 7;
        int k = kp * 2;
        const float* W = (which == 0) ? ((k < 128) ? W00 : W01) : ((k < 128) ? W10 : W11);
        uint* Wt = (which == 0) ? Wt0 : Wt1;
        int kk = k & 127;
        float f0 = W[(size_t)kk * 128 + col];
        float f1 = W[(size_t)(kk + 1) * 128 + col];
        Wt[(size_t)col * 128 + kp] = pk(f0, f1);
    } else {
        int i = (blockIdx.x - 128) * 256 + threadIdx.x;
        if (i < N) deg[i] = 0;
    }
}

// ---------------- degree + per-edge slot ----------------
__global__ void k_deg(const int* __restrict__ row, int* __restrict__ deg,
                      int* __restrict__ pos, int E) {
    int e = blockIdx.x * blockDim.x + threadIdx.x;
    if (e < E) pos[e] = atomicAdd(&deg[row[e]], 1);
}

// ---------------- x convert (+ inline dinv compute/store) ----------------
__global__ void k_cvt_x(const float4* __restrict__ X, const int* __restrict__ deg,
                        float* __restrict__ dinv,
                        uint2* __restrict__ Xb, uint2* __restrict__ Xsb, int n4) {
    int i = blockIdx.x * 256 + threadIdx.x;
    if (i >= n4) return;
    int node = i >> 5;
    int d = deg[node];
    float s = (d > 0) ? rsqrtf((float)d) : 0.0f;
    if ((i & 31) == 0) dinv[node] = s;
    float4 v = X[i];
    Xb[i]  = make_uint2(pk(v.x, v.y), pk(v.z, v.w));
    Xsb[i] = make_uint2(pk(v.x * s, v.y * s), pk(v.z * s, v.w * s));
}

// ---------------- rowStart: self-computed prefix base + in-block scan ----------------
__global__ void k_rowstart(const int* __restrict__ deg, int* __restrict__ rowStart, int N) {
    __shared__ int s[256];
    const int base0 = blockIdx.x * 256;
    int part = 0;
    for (int t = threadIdx.x; t < base0; t += 256) part += deg[t];
    s[threadIdx.x] = part;
    __syncthreads();
    for (int off = 128; off > 0; off >>= 1) {
        if (threadIdx.x < off) s[threadIdx.x] += s[threadIdx.x + off];
        __syncthreads();
    }
    const int base = s[0];
    __syncthreads();
    int i = base0 + threadIdx.x;
    int v = (i < N) ? deg[i] : 0;
    s[threadIdx.x] = v;
    __syncthreads();
    for (int off = 1; off < 256; off <<= 1) {
        int t = (threadIdx.x >= off) ? s[threadIdx.x - off] : 0;
        __syncthreads();
        s[threadIdx.x] += t;
        __syncthreads();
    }
    if (i < N) {
        int incl = s[threadIdx.x];
        rowStart[i] = base + incl - v;
        if (i == N - 1) rowStart[N] = base + incl;
    }
}

// ---------------- CSR fill: pure scatter, no atomics ----------------
__global__ void k_fill(const int* __restrict__ row, const int* __restrict__ col,
                       const int* __restrict__ rowStart, const int* __restrict__ pos,
                       int* __restrict__ csr, int E) {
    int e = blockIdx.x * blockDim.x + threadIdx.x;
    if (e < E) csr[rowStart[row[e]] + pos[e]] = col[e];
}

// ---------------- SpMM: Ob[i] = bf16( -dinv[i] * sum_j Xs[j] ) ----------------
// 32 lanes/row (lane owns uint2 = 4ch, 256B/neighbor), 2 rows/wave, unroll x8:
// 8 index loads hoisted, then 8 outstanding 256B gathers per row.
__global__ __launch_bounds__(256) void k_spmm(const uint2* __restrict__ Xs,
                                              const float* __restrict__ dinv,
                                              const int* __restrict__ rowStart,
                                              const int* __restrict__ csr,
                                              uint2* __restrict__ Ob, int N) {
    int r = (int)((blockIdx.x * 256 + threadIdx.x) >> 5);
    int l = threadIdx.x & 31;
    if (r >= N) return;
    int s = rowStart[r], e = rowStart[r + 1];
    float a0 = 0.f, a1 = 0.f, a2 = 0.f, a3 = 0.f;
    int k = s;
    for (; k + 8 <= e; k += 8) {
        int j0 = csr[k + 0], j1 = csr[k + 1], j2 = csr[k + 2], j3 = csr[k + 3];
        int j4 = csr[k + 4], j5 = csr[k + 5], j6 = csr[k + 6], j7 = csr[k + 7];
        uint2 v0 = Xs[(size_t)j0 * 32 + l];
        uint2 v1 = Xs[(size_t)j1 * 32 + l];
        uint2 v2 = Xs[(size_t)j2 * 32 + l];
        uint2 v3 = Xs[(size_t)j3 * 32 + l];
        uint2 v4 = Xs[(size_t)j4 * 32 + l];
        uint2 v5 = Xs[(size_t)j5 * 32 + l];
        uint2 v6 = Xs[(size_t)j6 * 32 + l];
        uint2 v7 = Xs[(size_t)j7 * 32 + l];
        a0 += ((blo(v0.x) + blo(v1.x)) + (blo(v2.x) + blo(v3.x)))
            + ((blo(v4.x) + blo(v5.x)) + (blo(v6.x) + blo(v7.x)));
        a1 += ((bhi(v0.x) + bhi(v1.x)) + (bhi(v2.x) + bhi(v3.x)))
            + ((bhi(v4.x) + bhi(v5.x)) + (bhi(v6.x) + bhi(v7.x)));
        a2 += ((blo(v0.y) + blo(v1.y)) + (blo(v2.y) + blo(v3.y)))
            + ((blo(v4.y) + blo(v5.y)) + (blo(v6.y) + blo(v7.y)));
        a3 += ((bhi(v0.y) + bhi(v1.y)) + (bhi(v2.y) + bhi(v3.y)))
            + ((bhi(v4.y) + bhi(v5.y)) + (bhi(v6.y) + bhi(v7.y)));
    }
    for (; k + 2 <= e; k += 2) {
        int j0 = csr[k + 0], j1 = csr[k + 1];
        uint2 v0 = Xs[(size_t)j0 * 32 + l];
        uint2 v1 = Xs[(size_t)j1 * 32 + l];
        a0 += blo(v0.x) + blo(v1.x);  a1 += bhi(v0.x) + bhi(v1.x);
        a2 += blo(v0.y) + blo(v1.y);  a3 += bhi(v0.y) + bhi(v1.y);
    }
    if (k < e) {
        int j = csr[k];
        uint2 v = Xs[(size_t)j * 32 + l];
        a0 += blo(v.x); a1 += bhi(v.x); a2 += blo(v.y); a3 += bhi(v.y);
    }
    float sc = -dinv[r];
    Ob[(size_t)r * 32 + l] = make_uint2(pk(a0 * sc, a1 * sc), pk(a2 * sc, a3 * sc));
}

// ---------------- MFMA GEMM: out = epi( [A1|A2] @ Wt^T + bias ) ----------------
__global__ __launch_bounds__(512) void k_gemm_mfma(const uint* __restrict__ A1,
                                                   const uint* __restrict__ A2,
                                                   const uint* __restrict__ Wt,
                                                   const float* __restrict__ bias,
                                                   const float* __restrict__ xres,
                                                   const float* __restrict__ dinv,
                                                   void* __restrict__ outp,
                                                   uint* __restrict__ outs,
                                                   int N, int mode) {
    __shared__ uint AsU[2][128 * 20];
    __shared__ uint WsU[2][128 * 20];

    const int tid = threadIdx.x;
    const int lane = tid & 63;
    const int wid = tid >> 6;
    const int wr = wid >> 1;
    const int wc = wid & 1;
    const int row0 = blockIdx.x * 128;
    const int l16 = lane & 15;
    const int lk = lane >> 4;

    f32x4 acc[2][4];
    #pragma unroll
    for (int m = 0; m < 2; m++)
        #pragma unroll
        for (int n = 0; n < 4; n++)
            acc[m][n] = (f32x4){0.f, 0.f, 0.f, 0.f};

    const int sr = tid >> 2;
    const int sc4 = tid & 3;
    const uint4* A1p = (const uint4*)A1;
    const uint4* A2p = (const uint4*)A2;
    const uint4* Wtp = (const uint4*)Wt;
    const int arow = min(row0 + sr, N - 1);

    uint4 ga, gw;
    ga = A1p[(size_t)arow * 16 + sc4];
    gw = Wtp[(size_t)sr * 32 + sc4];
    *(uint4*)&AsU[0][sr * 20 + sc4 * 4] = ga;
    *(uint4*)&WsU[0][sr * 20 + sc4 * 4] = gw;
    __syncthreads();

    for (int t = 0; t < 8; ++t) {
        const int cur = t & 1;
        if (t < 7) {
            const int k0 = (t + 1) * 32;
            const uint4* Ap = (k0 < 128) ? A1p : A2p;
            const int kk = k0 & 127;
            ga = Ap[(size_t)arow * 16 + (kk >> 3) + sc4];
            gw = Wtp[(size_t)sr * 32 + (k0 >> 3) + sc4];
        }

        bf16x8 bfr[4];
        #pragma unroll
        for (int n = 0; n < 4; n++) {
            int col = wc * 64 + n * 16 + l16;
            bfr[n] = *(const bf16x8*)&WsU[cur][col * 20 + lk * 4];
        }
        #pragma unroll
        for (int m = 0; m < 2; m++) {
            int row = wr * 32 + m * 16 + l16;
            bf16x8 afr = *(const bf16x8*)&AsU[cur][row * 20 + lk * 4];
            #pragma unroll
            for (int n = 0; n < 4; n++)
                acc[m][n] = __builtin_amdgcn_mfma_f32_16x16x32_bf16(afr, bfr[n], acc[m][n], 0, 0, 0);
        }

        if (t < 7) {
            *(uint4*)&AsU[cur ^ 1][sr * 20 + sc4 * 4] = ga;
            *(uint4*)&WsU[cur ^ 1][sr * 20 + sc4 * 4] = gw;
            __syncthreads();
        }
    }

    if (mode == 0) {
        ushort* O = (ushort*)outp;
        ushort* S = (ushort*)outs;
        #pragma unroll
        for (int m = 0; m < 2; m++) {
            #pragma unroll
            for (int r = 0; r < 4; r++) {
                int rg = row0 + wr * 32 + m * 16 + lk * 4 + r;
                if (rg >= N) continue;
                float sc = dinv[rg];
                #pragma unroll
                for (int n = 0; n < 4; n++) {
                    const int col = wc * 64 + n * 16 + l16;
                    float v = fmaxf(acc[m][n][r] + bias[col], 0.f);
                    O[(size_t)rg * 128 + col] = f2bf(v);
                    S[(size_t)rg * 128 + col] = f2bf(v * sc);
                }
            }
        }
    } else {
        float* O = (float*)outp;
        #pragma unroll
        for (int m = 0; m < 2; m++) {
            #pragma unroll
            for (int r = 0; r < 4; r++) {
                int rg = row0 + wr * 32 + m * 16 + lk * 4 + r;
                if (rg >= N) continue;
                #pragma unroll
                for (int n = 0; n < 4; n++) {
                    const int col = wc * 64 + n * 16 + l16;
                    float v = fmaxf(acc[m][n][r] + bias[col], 0.f);
                    O[(size_t)rg * 128 + col] = 0.5f * (v + xres[(size_t)rg * 128 + col]);
                }
            }
        }
    }
}

extern "C" void kernel_launch(void* const* d_in, const int* in_sizes, int n_in,
                              void* d_out, int out_size, void* d_ws, size_t ws_size,
                              hipStream_t stream) {
    const float* x   = (const float*)d_in[0];
    const int*   ei  = (const int*)d_in[1];
    const float* W00 = (const float*)d_in[2];
    const float* W01 = (const float*)d_in[3];
    const float* b0  = (const float*)d_in[4];
    const float* W10 = (const float*)d_in[5];
    const float* W11 = (const float*)d_in[6];
    const float* b1  = (const float*)d_in[7];
    float* out = (float*)d_out;

    const int N = in_sizes[0] / CH;   // 40000
    const int E = in_sizes[1] / 2;    // 640000
    const int* row = ei;
    const int* col = ei + E;

    char* ws = (char*)d_ws;
    size_t off = 0;
    auto alloc = [&](size_t bytes) -> void* {
        void* p = ws + off;
        off += (bytes + 255) & ~(size_t)255;
        return p;
    };
    int*   deg      = (int*)alloc((size_t)N * 4);
    float* dinv     = (float*)alloc((size_t)N * 4);
    int*   rowStart = (int*)alloc((size_t)(N + 1) * 4);
    int*   pos      = (int*)alloc((size_t)E * 4);
    int*   csr      = (int*)alloc((size_t)E * 4);
    uint*  xb       = (uint*)alloc((size_t)N * 64 * 4);
    uint*  xsb      = (uint*)alloc((size_t)N * 64 * 4);
    uint*  Lb       = (uint*)alloc((size_t)N * 64 * 4);
    uint*  yb       = (uint*)alloc((size_t)N * 64 * 4);
    uint*  ysb      = (uint*)alloc((size_t)N * 64 * 4);
    uint*  Wt0      = (uint*)alloc(128 * 128 * 4);
    uint*  Wt1      = (uint*)alloc(128 * 128 * 4);

    const int nB = (N + 255) / 256;   // 157

    k_prolog<<<128 + nB, 256, 0, stream>>>(W00, W01, W10, W11, Wt0, Wt1, deg, N);
    k_deg<<<(E + 255) / 256, 256, 0, stream>>>(row, deg, pos, E);
    k_cvt_x<<<(N * 32 + 255) / 256, 256, 0, stream>>>((const float4*)x, deg, dinv,
                                                      (uint2*)xb, (uint2*)xsb, N * 32);
    k_rowstart<<<nB, 256, 0, stream>>>(deg, rowStart, N);
    k_fill<<<(E + 255) / 256, 256, 0, stream>>>(row, col, rowStart, pos, csr, E);

    const int gemmBlocks = (N + 127) / 128;
    const int spmmBlocks = (N * 32 + 255) / 256;   // 5000

    // layer 1
    k_spmm<<<spmmBlocks, 256, 0, stream>>>((const uint2*)xsb, dinv, rowStart, csr,
                                           (uint2*)Lb, N);
    k_gemm_mfma<<<gemmBlocks, 512, 0, stream>>>(xb, Lb, Wt0, b0, nullptr, dinv,
                                                (void*)yb, ysb, N, 0);

    // layer 2
    k_spmm<<<spmmBlocks, 256, 0, stream>>>((const uint2*)ysb, dinv, rowStart, csr,
                                           (uint2*)Lb, N);
    k_gemm_mfma<<<gemmBlocks, 512, 0, stream>>>(yb, Lb, Wt1, b1, x, dinv,
                                                (void*)out, nullptr, N, 1);
}

// Round 8
// 140.489 us; speedup vs baseline: 1.5697x; 1.1072x over previous
//
#include <hip/hip_runtime.h>

#define CH 128

typedef unsigned int uint;
typedef unsigned short ushort;
typedef __attribute__((ext_vector_type(8))) short bf16x8;
typedef __attribute__((ext_vector_type(4))) float f32x4;

__device__ inline ushort f2bf(float f) {
    uint u = __float_as_uint(f);
    u += 0x7fffu + ((u >> 16) & 1u);     // RNE
    return (ushort)(u >> 16);
}
__device__ inline float blo(uint v) { return __uint_as_float(v << 16); }
__device__ inline float bhi(uint v) { return __uint_as_float(v & 0xffff0000u); }
__device__ inline uint pk(float a, float b) { return (uint)f2bf(a) | ((uint)f2bf(b) << 16); }

// ---------------- merged: weight transpose-convert (blocks 0..127) + deg zero (rest) ----------------
__global__ void k_prolog(const float* __restrict__ W00, const float* __restrict__ W01,
                         const float* __restrict__ W10, const float* __restrict__ W11,
                         uint* __restrict__ Wt0, uint* __restrict__ Wt1,
                         int* __restrict__ deg, int N) {
    if (blockIdx.x < 128) {
        int tid = blockIdx.x * 256 + threadIdx.x;      // 0..32767
        int which = tid >> 14;
        int t = tid & 16383;
        int col = t & 127, kp = t >> 7;
        int k = kp * 2;
        const float* W = (which == 0) ? ((k < 128) ? W00 : W01) : ((k < 128) ? W10 : W11);
        uint* Wt = (which == 0) ? Wt0 : Wt1;
        int kk = k & 127;
        float f0 = W[(size_t)kk * 128 + col];
        float f1 = W[(size_t)(kk + 1) * 128 + col];
        Wt[(size_t)col * 128 + kp] = pk(f0, f1);
    } else {
        int i = (blockIdx.x - 128) * 256 + threadIdx.x;
        if (i < N) deg[i] = 0;
    }
}

// ---------------- degree + per-edge slot ----------------
__global__ void k_deg(const int* __restrict__ row, int* __restrict__ deg,
                      int* __restrict__ pos, int E) {
    int e = blockIdx.x * blockDim.x + threadIdx.x;
    if (e < E) pos[e] = atomicAdd(&deg[row[e]], 1);
}

// ---------------- dinv + per-block degree sums ----------------
__global__ void k_dinv_bsum(const int* __restrict__ deg, float* __restrict__ dinv,
                            int* __restrict__ bsum, int N) {
    __shared__ int s[256];
    int i = blockIdx.x * 256 + threadIdx.x;
    int d = (i < N) ? deg[i] : 0;
    if (i < N) dinv[i] = (d > 0) ? rsqrtf((float)d) : 0.0f;
    s[threadIdx.x] = d;
    __syncthreads();
    for (int off = 128; off > 0; off >>= 1) {
        if (threadIdx.x < off) s[threadIdx.x] += s[threadIdx.x + off];
        __syncthreads();
    }
    if (threadIdx.x == 0) bsum[blockIdx.x] = s[0];
}

// ---------------- rowStart: redundant per-block scan of bsum (no extra launch, no serial chain) ----
__global__ void k_rowstart(const int* __restrict__ deg, const int* __restrict__ bsum,
                           int* __restrict__ rowStart, int N, int nB) {
    __shared__ int s[256];
    // phase 1: every block scans the (<=256) block sums in LDS, takes its own exclusive prefix
    int v = (threadIdx.x < nB) ? bsum[threadIdx.x] : 0;
    s[threadIdx.x] = v;
    __syncthreads();
    for (int off = 1; off < 256; off <<= 1) {
        int t = (threadIdx.x >= off) ? s[threadIdx.x - off] : 0;
        __syncthreads();
        s[threadIdx.x] += t;
        __syncthreads();
    }
    const int base = (blockIdx.x == 0) ? 0 : s[blockIdx.x - 1];
    __syncthreads();
    // phase 2: in-block inclusive scan of deg
    int i = blockIdx.x * 256 + threadIdx.x;
    int d = (i < N) ? deg[i] : 0;
    s[threadIdx.x] = d;
    __syncthreads();
    for (int off = 1; off < 256; off <<= 1) {
        int t = (threadIdx.x >= off) ? s[threadIdx.x - off] : 0;
        __syncthreads();
        s[threadIdx.x] += t;
        __syncthreads();
    }
    if (i < N) {
        int incl = s[threadIdx.x];
        rowStart[i] = base + incl - d;
        if (i == N - 1) rowStart[N] = base + incl;
    }
}

// ---------------- CSR fill: pure scatter, no atomics ----------------
__global__ void k_fill(const int* __restrict__ row, const int* __restrict__ col,
                       const int* __restrict__ rowStart, const int* __restrict__ pos,
                       int* __restrict__ csr, int E) {
    int e = blockIdx.x * blockDim.x + threadIdx.x;
    if (e < E) csr[rowStart[row[e]] + pos[e]] = col[e];
}

// ---------------- x convert (reads precomputed dinv) ----------------
__global__ void k_cvt_x(const float4* __restrict__ X, const float* __restrict__ dinv,
                        uint2* __restrict__ Xb, uint2* __restrict__ Xsb, int n4) {
    int i = blockIdx.x * 256 + threadIdx.x;
    if (i >= n4) return;
    float4 v = X[i];
    float s = dinv[i >> 5];
    Xb[i]  = make_uint2(pk(v.x, v.y), pk(v.z, v.w));
    Xsb[i] = make_uint2(pk(v.x * s, v.y * s), pk(v.z * s, v.w * s));
}

// ---------------- SpMM: Ob[i] = bf16( -dinv[i] * sum_j Xs[j] ) ----------------
// 32 lanes/row (lane owns uint2 = 4ch, 256B/neighbor), 2 rows/wave, unroll x4.  [R4-exact]
__global__ __launch_bounds__(256) void k_spmm(const uint2* __restrict__ Xs,
                                              const float* __restrict__ dinv,
                                              const int* __restrict__ rowStart,
                                              const int* __restrict__ csr,
                                              uint2* __restrict__ Ob, int N) {
    int r = (int)((blockIdx.x * 256 + threadIdx.x) >> 5);
    int l = threadIdx.x & 31;
    if (r >= N) return;
    int s = rowStart[r], e = rowStart[r + 1];
    float a0 = 0.f, a1 = 0.f, a2 = 0.f, a3 = 0.f;
    int k = s;
    for (; k + 4 <= e; k += 4) {
        int j0 = csr[k + 0], j1 = csr[k + 1], j2 = csr[k + 2], j3 = csr[k + 3];
        uint2 v0 = Xs[(size_t)j0 * 32 + l];
        uint2 v1 = Xs[(size_t)j1 * 32 + l];
        uint2 v2 = Xs[(size_t)j2 * 32 + l];
        uint2 v3 = Xs[(size_t)j3 * 32 + l];
        a0 += (blo(v0.x) + blo(v1.x)) + (blo(v2.x) + blo(v3.x));
        a1 += (bhi(v0.x) + bhi(v1.x)) + (bhi(v2.x) + bhi(v3.x));
        a2 += (blo(v0.y) + blo(v1.y)) + (blo(v2.y) + blo(v3.y));
        a3 += (bhi(v0.y) + bhi(v1.y)) + (bhi(v2.y) + bhi(v3.y));
    }
    for (; k < e; ++k) {
        int j = csr[k];
        uint2 v = Xs[(size_t)j * 32 + l];
        a0 += blo(v.x); a1 += bhi(v.x); a2 += blo(v.y); a3 += bhi(v.y);
    }
    float sc = -dinv[r];
    Ob[(size_t)r * 32 + l] = make_uint2(pk(a0 * sc, a1 * sc), pk(a2 * sc, a3 * sc));
}

// ---------------- MFMA GEMM: out = epi( [A1|A2] @ Wt^T + bias ) ----------------
__global__ __launch_bounds__(512) void k_gemm_mfma(const uint* __restrict__ A1,
                                                   const uint* __restrict__ A2,
                                                   const uint* __restrict__ Wt,
                                                   const float* __restrict__ bias,
                                                   const float* __restrict__ xres,
                                                   const float* __restrict__ dinv,
                                                   void* __restrict__ outp,
                                                   uint* __restrict__ outs,
                                                   int N, int mode) {
    __shared__ uint AsU[2][128 * 20];
    __shared__ uint WsU[2][128 * 20];

    const int tid = threadIdx.x;
    const int lane = tid & 63;
    const int wid = tid >> 6;
    const int wr = wid >> 1;
    const int wc = wid & 1;
    const int row0 = blockIdx.x * 128;
    const int l16 = lane & 15;
    const int lk = lane >> 4;

    f32x4 acc[2][4];
    #pragma unroll
    for (int m = 0; m < 2; m++)
        #pragma unroll
        for (int n = 0; n < 4; n++)
            acc[m][n] = (f32x4){0.f, 0.f, 0.f, 0.f};

    const int sr = tid >> 2;
    const int sc4 = tid & 3;
    const uint4* A1p = (const uint4*)A1;
    const uint4* A2p = (const uint4*)A2;
    const uint4* Wtp = (const uint4*)Wt;
    const int arow = min(row0 + sr, N - 1);

    uint4 ga, gw;
    ga = A1p[(size_t)arow * 16 + sc4];
    gw = Wtp[(size_t)sr * 32 + sc4];
    *(uint4*)&AsU[0][sr * 20 + sc4 * 4] = ga;
    *(uint4*)&WsU[0][sr * 20 + sc4 * 4] = gw;
    __syncthreads();

    for (int t = 0; t < 8; ++t) {
        const int cur = t & 1;
        if (t < 7) {
            const int k0 = (t + 1) * 32;
            const uint4* Ap = (k0 < 128) ? A1p : A2p;
            const int kk = k0 & 127;
            ga = Ap[(size_t)arow * 16 + (kk >> 3) + sc4];
            gw = Wtp[(size_t)sr * 32 + (k0 >> 3) + sc4];
        }

        bf16x8 bfr[4];
        #pragma unroll
        for (int n = 0; n < 4; n++) {
            int col = wc * 64 + n * 16 + l16;
            bfr[n] = *(const bf16x8*)&WsU[cur][col * 20 + lk * 4];
        }
        #pragma unroll
        for (int m = 0; m < 2; m++) {
            int row = wr * 32 + m * 16 + l16;
            bf16x8 afr = *(const bf16x8*)&AsU[cur][row * 20 + lk * 4];
            #pragma unroll
            for (int n = 0; n < 4; n++)
                acc[m][n] = __builtin_amdgcn_mfma_f32_16x16x32_bf16(afr, bfr[n], acc[m][n], 0, 0, 0);
        }

        if (t < 7) {
            *(uint4*)&AsU[cur ^ 1][sr * 20 + sc4 * 4] = ga;
            *(uint4*)&WsU[cur ^ 1][sr * 20 + sc4 * 4] = gw;
            __syncthreads();
        }
    }

    if (mode == 0) {
        ushort* O = (ushort*)outp;
        ushort* S = (ushort*)outs;
        #pragma unroll
        for (int m = 0; m < 2; m++) {
            #pragma unroll
            for (int r = 0; r < 4; r++) {
                int rg = row0 + wr * 32 + m * 16 + lk * 4 + r;
                if (rg >= N) continue;
                float sc = dinv[rg];
                #pragma unroll
                for (int n = 0; n < 4; n++) {
                    const int col = wc * 64 + n * 16 + l16;
                    float v = fmaxf(acc[m][n][r] + bias[col], 0.f);
                    O[(size_t)rg * 128 + col] = f2bf(v);
                    S[(size_t)rg * 128 + col] = f2bf(v * sc);
                }
            }
        }
    } else {
        float* O = (float*)outp;
        #pragma unroll
        for (int m = 0; m < 2; m++) {
            #pragma unroll
            for (int r = 0; r < 4; r++) {
                int rg = row0 + wr * 32 + m * 16 + lk * 4 + r;
                if (rg >= N) continue;
                #pragma unroll
                for (int n = 0; n < 4; n++) {
                    const int col = wc * 64 + n * 16 + l16;
                    float v = fmaxf(acc[m][n][r] + bias[col], 0.f);
                    O[(size_t)rg * 128 + col] = 0.5f * (v + xres[(size_t)rg * 128 + col]);
                }
            }
        }
    }
}

extern "C" void kernel_launch(void* const* d_in, const int* in_sizes, int n_in,
                              void* d_out, int out_size, void* d_ws, size_t ws_size,
                              hipStream_t stream) {
    const float* x   = (const float*)d_in[0];
    const int*   ei  = (const int*)d_in[1];
    const float* W00 = (const float*)d_in[2];
    const float* W01 = (const float*)d_in[3];
    const float* b0  = (const float*)d_in[4];
    const float* W10 = (const float*)d_in[5];
    const float* W11 = (const float*)d_in[6];
    const float* b1  = (const float*)d_in[7];
    float* out = (float*)d_out;

    const int N = in_sizes[0] / CH;   // 40000
    const int E = in_sizes[1] / 2;    // 640000
    const int* row = ei;
    const int* col = ei + E;

    char* ws = (char*)d_ws;
    size_t off = 0;
    auto alloc = [&](size_t bytes) -> void* {
        void* p = ws + off;
        off += (bytes + 255) & ~(size_t)255;
        return p;
    };
    int*   deg      = (int*)alloc((size_t)N * 4);
    float* dinv     = (float*)alloc((size_t)N * 4);
    int*   rowStart = (int*)alloc((size_t)(N + 1) * 4);
    int*   pos      = (int*)alloc((size_t)E * 4);
    int*   bsum     = (int*)alloc(4096);
    int*   csr      = (int*)alloc((size_t)E * 4);
    uint*  xb       = (uint*)alloc((size_t)N * 64 * 4);
    uint*  xsb      = (uint*)alloc((size_t)N * 64 * 4);
    uint*  Lb       = (uint*)alloc((size_t)N * 64 * 4);
    uint*  yb       = (uint*)alloc((size_t)N * 64 * 4);
    uint*  ysb      = (uint*)alloc((size_t)N * 64 * 4);
    uint*  Wt0      = (uint*)alloc(128 * 128 * 4);
    uint*  Wt1      = (uint*)alloc(128 * 128 * 4);

    const int nB = (N + 255) / 256;   // 157 <= 256

    k_prolog<<<128 + nB, 256, 0, stream>>>(W00, W01, W10, W11, Wt0, Wt1, deg, N);
    k_deg<<<(E + 255) / 256, 256, 0, stream>>>(row, deg, pos, E);
    k_dinv_bsum<<<nB, 256, 0, stream>>>(deg, dinv, bsum, N);
    k_rowstart<<<nB, 256, 0, stream>>>(deg, bsum, rowStart, N, nB);
    k_fill<<<(E + 255) / 256, 256, 0, stream>>>(row, col, rowStart, pos, csr, E);
    k_cvt_x<<<(N * 32 + 255) / 256, 256, 0, stream>>>((const float4*)x, dinv,
                                                      (uint2*)xb, (uint2*)xsb, N * 32);

    const int gemmBlocks = (N + 127) / 128;
    const int spmmBlocks = (N * 32 + 255) / 256;   // 5000

    // layer 1
    k_spmm<<<spmmBlocks, 256, 0, stream>>>((const uint2*)xsb, dinv, rowStart, csr,
                                           (uint2*)Lb, N);
    k_gemm_mfma<<<gemmBlocks, 512, 0, stream>>>(xb, Lb, Wt0, b0, nullptr, dinv,
                                                (void*)yb, ysb, N, 0);

    // layer 2
    k_spmm<<<spmmBlocks, 256, 0, stream>>>((const uint2*)ysb, dinv, rowStart, csr,
                                           (uint2*)Lb, N);
    k_gemm_mfma<<<gemmBlocks, 512, 0, stream>>>(yb, Lb, Wt1, b1, x, dinv,
                                                (void*)out, nullptr, N, 1);
}

// Round 9
// 132.680 us; speedup vs baseline: 1.6621x; 1.0589x over previous
//
#include <hip/hip_runtime.h>

#define CH 128

typedef unsigned int uint;
typedef unsigned short ushort;
typedef __attribute__((ext_vector_type(8))) short bf16x8;
typedef __attribute__((ext_vector_type(4))) float f32x4;

__device__ inline ushort f2bf(float f) {
    uint u = __float_as_uint(f);
    u += 0x7fffu + ((u >> 16) & 1u);     // RNE
    return (ushort)(u >> 16);
}
__device__ inline float blo(uint v) { return __uint_as_float(v << 16); }
__device__ inline float bhi(uint v) { return __uint_as_float(v & 0xffff0000u); }
__device__ inline uint pk(float a, float b) { return (uint)f2bf(a) | ((uint)f2bf(b) << 16); }

// ---------------- merged: weight transpose-convert (blocks 0..127) + deg zero (rest) ----------------
__global__ void k_prolog(const float* __restrict__ W00, const float* __restrict__ W01,
                         const float* __restrict__ W10, const float* __restrict__ W11,
                         uint* __restrict__ Wt0, uint* __restrict__ Wt1,
                         int* __restrict__ deg, int N) {
    if (blockIdx.x < 128) {
        int tid = blockIdx.x * 256 + threadIdx.x;      // 0..32767
        int which = tid >> 14;
        int t = tid & 16383;
        int col = t & 127, kp = t >> 7;
        int k = kp * 2;
        const float* W = (which == 0) ? ((k < 128) ? W00 : W01) : ((k < 128) ? W10 : W11);
        uint* Wt = (which == 0) ? Wt0 : Wt1;
        int kk = k & 127;
        float f0 = W[(size_t)kk * 128 + col];
        float f1 = W[(size_t)(kk + 1) * 128 + col];
        Wt[(size_t)col * 128 + kp] = pk(f0, f1);
    } else {
        int i = (blockIdx.x - 128) * 256 + threadIdx.x;
        if (i < N) deg[i] = 0;
    }
}

// ---------------- degree + per-edge slot ----------------
__global__ void k_deg(const int* __restrict__ row, int* __restrict__ deg,
                      int* __restrict__ pos, int E) {
    int e = blockIdx.x * blockDim.x + threadIdx.x;
    if (e < E) pos[e] = atomicAdd(&deg[row[e]], 1);
}

// ---------------- dinv + per-block degree sums ----------------
__global__ void k_dinv_bsum(const int* __restrict__ deg, float* __restrict__ dinv,
                            int* __restrict__ bsum, int N) {
    __shared__ int s[256];
    int i = blockIdx.x * 256 + threadIdx.x;
    int d = (i < N) ? deg[i] : 0;
    if (i < N) dinv[i] = (d > 0) ? rsqrtf((float)d) : 0.0f;
    s[threadIdx.x] = d;
    __syncthreads();
    for (int off = 128; off > 0; off >>= 1) {
        if (threadIdx.x < off) s[threadIdx.x] += s[threadIdx.x + off];
        __syncthreads();
    }
    if (threadIdx.x == 0) bsum[blockIdx.x] = s[0];
}

// ---------------- merged: rowStart (blocks < nB) | x convert (blocks >= nB) ----------------
__global__ void k_rs_cvt(const int* __restrict__ deg, const int* __restrict__ bsum,
                         int* __restrict__ rowStart,
                         const float4* __restrict__ X, const float* __restrict__ dinv,
                         uint2* __restrict__ Xb, uint2* __restrict__ Xsb,
                         int N, int nB, int n4) {
    if ((int)blockIdx.x < nB) {
        __shared__ int s[256];
        // phase 1: scan the (<=256) block sums, take this block's exclusive prefix
        int v = ((int)threadIdx.x < nB) ? bsum[threadIdx.x] : 0;
        s[threadIdx.x] = v;
        __syncthreads();
        for (int off = 1; off < 256; off <<= 1) {
            int t = (threadIdx.x >= off) ? s[threadIdx.x - off] : 0;
            __syncthreads();
            s[threadIdx.x] += t;
            __syncthreads();
        }
        const int base = (blockIdx.x == 0) ? 0 : s[blockIdx.x - 1];
        __syncthreads();
        // phase 2: in-block inclusive scan of deg
        int i = blockIdx.x * 256 + threadIdx.x;
        int d = (i < N) ? deg[i] : 0;
        s[threadIdx.x] = d;
        __syncthreads();
        for (int off = 1; off < 256; off <<= 1) {
            int t = (threadIdx.x >= off) ? s[threadIdx.x - off] : 0;
            __syncthreads();
            s[threadIdx.x] += t;
            __syncthreads();
        }
        if (i < N) {
            int incl = s[threadIdx.x];
            rowStart[i] = base + incl - d;
            if (i == N - 1) rowStart[N] = base + incl;
        }
    } else {
        int i = ((int)blockIdx.x - nB) * 256 + threadIdx.x;
        if (i >= n4) return;
        float4 v = X[i];
        float s = dinv[i >> 5];
        Xb[i]  = make_uint2(pk(v.x, v.y), pk(v.z, v.w));
        Xsb[i] = make_uint2(pk(v.x * s, v.y * s), pk(v.z * s, v.w * s));
    }
}

// ---------------- CSR fill: pure scatter, no atomics ----------------
__global__ void k_fill(const int* __restrict__ row, const int* __restrict__ col,
                       const int* __restrict__ rowStart, const int* __restrict__ pos,
                       int* __restrict__ csr, int E) {
    int e = blockIdx.x * blockDim.x + threadIdx.x;
    if (e < E) csr[rowStart[row[e]] + pos[e]] = col[e];
}

// ---------------- SpMM: Ob[i] = bf16( -dinv[i] * sum_j Xs[j] ) ----------------
// 32 lanes/row (lane owns uint2 = 4ch, 256B/neighbor), 2 rows/wave, unroll x4.  [R4-exact]
__global__ __launch_bounds__(256) void k_spmm(const uint2* __restrict__ Xs,
                                              const float* __restrict__ dinv,
                                              const int* __restrict__ rowStart,
                                              const int* __restrict__ csr,
                                              uint2* __restrict__ Ob, int N) {
    int r = (int)((blockIdx.x * 256 + threadIdx.x) >> 5);
    int l = threadIdx.x & 31;
    if (r >= N) return;
    int s = rowStart[r], e = rowStart[r + 1];
    float a0 = 0.f, a1 = 0.f, a2 = 0.f, a3 = 0.f;
    int k = s;
    for (; k + 4 <= e; k += 4) {
        int j0 = csr[k + 0], j1 = csr[k + 1], j2 = csr[k + 2], j3 = csr[k + 3];
        uint2 v0 = Xs[(size_t)j0 * 32 + l];
        uint2 v1 = Xs[(size_t)j1 * 32 + l];
        uint2 v2 = Xs[(size_t)j2 * 32 + l];
        uint2 v3 = Xs[(size_t)j3 * 32 + l];
        a0 += (blo(v0.x) + blo(v1.x)) + (blo(v2.x) + blo(v3.x));
        a1 += (bhi(v0.x) + bhi(v1.x)) + (bhi(v2.x) + bhi(v3.x));
        a2 += (blo(v0.y) + blo(v1.y)) + (blo(v2.y) + blo(v3.y));
        a3 += (bhi(v0.y) + bhi(v1.y)) + (bhi(v2.y) + bhi(v3.y));
    }
    for (; k < e; ++k) {
        int j = csr[k];
        uint2 v = Xs[(size_t)j * 32 + l];
        a0 += blo(v.x); a1 += bhi(v.x); a2 += blo(v.y); a3 += bhi(v.y);
    }
    float sc = -dinv[r];
    Ob[(size_t)r * 32 + l] = make_uint2(pk(a0 * sc, a1 * sc), pk(a2 * sc, a3 * sc));
}

// ---------------- MFMA GEMM: out = epi( [A1|A2] @ Wt^T + bias ) ----------------
// Tile 64 rows x 128 cols, 256 threads (4 waves, each 32x64). Grid 625 -> better CU balance.
__global__ __launch_bounds__(256) void k_gemm_mfma(const uint* __restrict__ A1,
                                                   const uint* __restrict__ A2,
                                                   const uint* __restrict__ Wt,
                                                   const float* __restrict__ bias,
                                                   const float* __restrict__ xres,
                                                   const float* __restrict__ dinv,
                                                   void* __restrict__ outp,
                                                   uint* __restrict__ outs,
                                                   int N, int mode) {
    __shared__ uint AsU[2][64 * 20];
    __shared__ uint WsU[2][128 * 20];

    const int tid = threadIdx.x;
    const int lane = tid & 63;
    const int wid = tid >> 6;       // 0..3
    const int wr = wid >> 1;        // 0..1
    const int wc = wid & 1;         // 0..1
    const int row0 = blockIdx.x * 64;
    const int l16 = lane & 15;
    const int lk = lane >> 4;       // 0..3

    f32x4 acc[2][4];
    #pragma unroll
    for (int m = 0; m < 2; m++)
        #pragma unroll
        for (int n = 0; n < 4; n++)
            acc[m][n] = (f32x4){0.f, 0.f, 0.f, 0.f};

    const int sra = tid >> 2;       // 0..63 A-row
    const int sca = tid & 3;        // 16B chunk in 32-k slab
    const uint4* A1p = (const uint4*)A1;
    const uint4* A2p = (const uint4*)A2;
    const uint4* Wtp = (const uint4*)Wt;
    const int arow = min(row0 + sra, N - 1);

    uint4 ga, gw0, gw1;
    ga  = A1p[(size_t)arow * 16 + sca];
    {
        int idx0 = tid, idx1 = tid + 256;
        gw0 = Wtp[(size_t)(idx0 >> 2) * 32 + (idx0 & 3)];
        gw1 = Wtp[(size_t)(idx1 >> 2) * 32 + (idx1 & 3)];
        *(uint4*)&AsU[0][sra * 20 + sca * 4] = ga;
        *(uint4*)&WsU[0][(idx0 >> 2) * 20 + (idx0 & 3) * 4] = gw0;
        *(uint4*)&WsU[0][(idx1 >> 2) * 20 + (idx1 & 3) * 4] = gw1;
    }
    __syncthreads();

    for (int t = 0; t < 8; ++t) {
        const int cur = t & 1;
        if (t < 7) {
            const int k0 = (t + 1) * 32;
            const uint4* Ap = (k0 < 128) ? A1p : A2p;
            const int kk = k0 & 127;
            ga  = Ap[(size_t)arow * 16 + (kk >> 3) + sca];
            int idx0 = tid, idx1 = tid + 256;
            gw0 = Wtp[(size_t)(idx0 >> 2) * 32 + (k0 >> 3) + (idx0 & 3)];
            gw1 = Wtp[(size_t)(idx1 >> 2) * 32 + (k0 >> 3) + (idx1 & 3)];
        }

        bf16x8 bfr[4];
        #pragma unroll
        for (int n = 0; n < 4; n++) {
            int col = wc * 64 + n * 16 + l16;
            bfr[n] = *(const bf16x8*)&WsU[cur][col * 20 + lk * 4];
        }
        #pragma unroll
        for (int m = 0; m < 2; m++) {
            int row = wr * 32 + m * 16 + l16;
            bf16x8 afr = *(const bf16x8*)&AsU[cur][row * 20 + lk * 4];
            #pragma unroll
            for (int n = 0; n < 4; n++)
                acc[m][n] = __builtin_amdgcn_mfma_f32_16x16x32_bf16(afr, bfr[n], acc[m][n], 0, 0, 0);
        }

        if (t < 7) {
            int idx0 = tid, idx1 = tid + 256;
            *(uint4*)&AsU[cur ^ 1][sra * 20 + sca * 4] = ga;
            *(uint4*)&WsU[cur ^ 1][(idx0 >> 2) * 20 + (idx0 & 3) * 4] = gw0;
            *(uint4*)&WsU[cur ^ 1][(idx1 >> 2) * 20 + (idx1 & 3) * 4] = gw1;
            __syncthreads();
        }
    }

    if (mode == 0) {
        ushort* O = (ushort*)outp;
        ushort* S = (ushort*)outs;
        #pragma unroll
        for (int m = 0; m < 2; m++) {
            #pragma unroll
            for (int r = 0; r < 4; r++) {
                int rg = row0 + wr * 32 + m * 16 + lk * 4 + r;
                if (rg >= N) continue;
                float sc = dinv[rg];
                #pragma unroll
                for (int n = 0; n < 4; n++) {
                    const int col = wc * 64 + n * 16 + l16;
                    float v = fmaxf(acc[m][n][r] + bias[col], 0.f);
                    O[(size_t)rg * 128 + col] = f2bf(v);
                    S[(size_t)rg * 128 + col] = f2bf(v * sc);
                }
            }
        }
    } else {
        float* O = (float*)outp;
        #pragma unroll
        for (int m = 0; m < 2; m++) {
            #pragma unroll
            for (int r = 0; r < 4; r++) {
                int rg = row0 + wr * 32 + m * 16 + lk * 4 + r;
                if (rg >= N) continue;
                #pragma unroll
                for (int n = 0; n < 4; n++) {
                    const int col = wc * 64 + n * 16 + l16;
                    float v = fmaxf(acc[m][n][r] + bias[col], 0.f);
                    O[(size_t)rg * 128 + col] = 0.5f * (v + xres[(size_t)rg * 128 + col]);
                }
            }
        }
    }
}

extern "C" void kernel_launch(void* const* d_in, const int* in_sizes, int n_in,
                              void* d_out, int out_size, void* d_ws, size_t ws_size,
                              hipStream_t stream) {
    const float* x   = (const float*)d_in[0];
    const int*   ei  = (const int*)d_in[1];
    const float* W00 = (const float*)d_in[2];
    const float* W01 = (const float*)d_in[3];
    const float* b0  = (const float*)d_in[4];
    const float* W10 = (const float*)d_in[5];
    const float* W11 = (const float*)d_in[6];
    const float* b1  = (const float*)d_in[7];
    float* out = (float*)d_out;

    const int N = in_sizes[0] / CH;   // 40000
    const int E = in_sizes[1] / 2;    // 640000
    const int* row = ei;
    const int* col = ei + E;

    char* ws = (char*)d_ws;
    size_t off = 0;
    auto alloc = [&](size_t bytes) -> void* {
        void* p = ws + off;
        off += (bytes + 255) & ~(size_t)255;
        return p;
    };
    int*   deg      = (int*)alloc((size_t)N * 4);
    float* dinv     = (float*)alloc((size_t)N * 4);
    int*   rowStart = (int*)alloc((size_t)(N + 1) * 4);
    int*   pos      = (int*)alloc((size_t)E * 4);
    int*   bsum     = (int*)alloc(4096);
    int*   csr      = (int*)alloc((size_t)E * 4);
    uint*  xb       = (uint*)alloc((size_t)N * 64 * 4);
    uint*  xsb      = (uint*)alloc((size_t)N * 64 * 4);
    uint*  Lb       = (uint*)alloc((size_t)N * 64 * 4);
    uint*  yb       = (uint*)alloc((size_t)N * 64 * 4);
    uint*  ysb      = (uint*)alloc((size_t)N * 64 * 4);
    uint*  Wt0      = (uint*)alloc(128 * 128 * 4);
    uint*  Wt1      = (uint*)alloc(128 * 128 * 4);

    const int nB = (N + 255) / 256;       // 157 <= 256
    const int n4 = N * 32;                // uint2 elements in x
    const int cvtB = (n4 + 255) / 256;    // 5000

    k_prolog<<<128 + nB, 256, 0, stream>>>(W00, W01, W10, W11, Wt0, Wt1, deg, N);
    k_deg<<<(E + 255) / 256, 256, 0, stream>>>(row, deg, pos, E);
    k_dinv_bsum<<<nB, 256, 0, stream>>>(deg, dinv, bsum, N);
    k_rs_cvt<<<nB + cvtB, 256, 0, stream>>>(deg, bsum, rowStart,
                                            (const float4*)x, dinv,
                                            (uint2*)xb, (uint2*)xsb, N, nB, n4);
    k_fill<<<(E + 255) / 256, 256, 0, stream>>>(row, col, rowStart, pos, csr, E);

    const int gemmBlocks = (N + 63) / 64;          // 625
    const int spmmBlocks = (N * 32 + 255) / 256;   // 5000

    // layer 1
    k_spmm<<<spmmBlocks, 256, 0, stream>>>((const uint2*)xsb, dinv, rowStart, csr,
                                           (uint2*)Lb, N);
    k_gemm_mfma<<<gemmBlocks, 256, 0, stream>>>(xb, Lb, Wt0, b0, nullptr, dinv,
                                                (void*)yb, ysb, N, 0);

    // layer 2
    k_spmm<<<spmmBlocks, 256, 0, stream>>>((const uint2*)ysb, dinv, rowStart, csr,
                                           (uint2*)Lb, N);
    k_gemm_mfma<<<gemmBlocks, 256, 0, stream>>>(yb, Lb, Wt1, b1, x, dinv,
                                                (void*)out, nullptr, N, 1);
}

// Round 10
// 121.012 us; speedup vs baseline: 1.8224x; 1.0964x over previous
//
#include <hip/hip_runtime.h>

#define CH 128

typedef unsigned int uint;
typedef unsigned short ushort;
typedef unsigned char uchar;
typedef __attribute__((ext_vector_type(8))) short bf16x8;
typedef __attribute__((ext_vector_type(4))) float f32x4;
typedef __attribute__((ext_vector_type(2))) float f32x2;

__device__ inline ushort f2bf(float f) {
    uint u = __float_as_uint(f);
    u += 0x7fffu + ((u >> 16) & 1u);     // RNE
    return (ushort)(u >> 16);
}
__device__ inline float blo(uint v) { return __uint_as_float(v << 16); }
__device__ inline float bhi(uint v) { return __uint_as_float(v & 0xffff0000u); }
__device__ inline uint pk(float a, float b) { return (uint)f2bf(a) | ((uint)f2bf(b) << 16); }

// ---------------- fp8 e4m3 (OCP) helpers ----------------
#if defined(__has_builtin)
#if __has_builtin(__builtin_amdgcn_cvt_pk_f32_fp8) && __has_builtin(__builtin_amdgcn_cvt_pk_fp8_f32)
#define HAVE_FP8_CVT 1
#endif
#endif

__device__ inline uint f32_to_fp8_manual(float f) {
    uint u = __float_as_uint(f);
    uint s = (u >> 24) & 0x80u;
    float a = fabsf(f);
    if (a < 0x1.0p-10f) return s;
    if (a >= 448.f) return s | 0x7eu;
    if (a < 0x1.0p-6f) {                       // e4m3 subnormal: m = round(a*512)
        uint m = (uint)(a * 512.f + 0.5f);
        return s | m;
    }
    uint au = u & 0x7fffffffu;
    uint r = au + 0x7ffffu + ((au >> 20) & 1u);  // RNE to 3-bit mantissa
    uint e = (r >> 23) - 120u;
    return s | (e << 3) | ((r >> 20) & 7u);
}
__device__ inline float fp8_to_f32_manual(uint b) {
    uint s = (b & 0x80u) << 24;
    uint em = (b & 0x7fu) << 20;
    return __uint_as_float(s | em) * 0x1.0p+120f;
}

__device__ inline uint pk_fp8x4(float a, float b, float c, float d) {
#ifdef HAVE_FP8_CVT
    uint r = __builtin_amdgcn_cvt_pk_fp8_f32(a, b, 0u, false);
    r = __builtin_amdgcn_cvt_pk_fp8_f32(c, d, r, true);
    return r;
#else
    return f32_to_fp8_manual(a) | (f32_to_fp8_manual(b) << 8) |
           (f32_to_fp8_manual(c) << 16) | (f32_to_fp8_manual(d) << 24);
#endif
}
__device__ inline uchar f2fp8(float a) {
#ifdef HAVE_FP8_CVT
    return (uchar)(__builtin_amdgcn_cvt_pk_fp8_f32(a, a, 0u, false) & 0xffu);
#else
    return (uchar)f32_to_fp8_manual(a);
#endif
}
__device__ inline void fp8x4_acc(uint v, f32x2& a01, f32x2& a23) {
#ifdef HAVE_FP8_CVT
    f32x2 p0 = __builtin_amdgcn_cvt_pk_f32_fp8((int)v, false);
    f32x2 p1 = __builtin_amdgcn_cvt_pk_f32_fp8((int)v, true);
    a01 += p0; a23 += p1;
#else
    a01[0] += fp8_to_f32_manual(v & 0xffu);
    a01[1] += fp8_to_f32_manual((v >> 8) & 0xffu);
    a23[0] += fp8_to_f32_manual((v >> 16) & 0xffu);
    a23[1] += fp8_to_f32_manual(v >> 24);
#endif
}

// ---------------- merged: weight transpose-convert (blocks 0..127) + deg zero (rest) ----------------
__global__ void k_prolog(const float* __restrict__ W00, const float* __restrict__ W01,
                         const float* __restrict__ W10, const float* __restrict__ W11,
                         uint* __restrict__ Wt0, uint* __restrict__ Wt1,
                         int* __restrict__ deg, int N) {
    if (blockIdx.x < 128) {
        int tid = blockIdx.x * 256 + threadIdx.x;      // 0..32767
        int which = tid >> 14;
        int t = tid & 16383;
        int col = t & 127, kp = t >> 7;
        int k = kp * 2;
        const float* W = (which == 0) ? ((k < 128) ? W00 : W01) : ((k < 128) ? W10 : W11);
        uint* Wt = (which == 0) ? Wt0 : Wt1;
        int kk = k & 127;
        float f0 = W[(size_t)kk * 128 + col];
        float f1 = W[(size_t)(kk + 1) * 128 + col];
        Wt[(size_t)col * 128 + kp] = pk(f0, f1);
    } else {
        int i = (blockIdx.x - 128) * 256 + threadIdx.x;
        if (i < N) deg[i] = 0;
    }
}

// ---------------- degree + per-edge slot ----------------
__global__ void k_deg(const int* __restrict__ row, int* __restrict__ deg,
                      int* __restrict__ pos, int E) {
    int e = blockIdx.x * blockDim.x + threadIdx.x;
    if (e < E) pos[e] = atomicAdd(&deg[row[e]], 1);
}

// ---------------- dinv + per-block degree sums ----------------
__global__ void k_dinv_bsum(const int* __restrict__ deg, float* __restrict__ dinv,
                            int* __restrict__ bsum, int N) {
    __shared__ int s[256];
    int i = blockIdx.x * 256 + threadIdx.x;
    int d = (i < N) ? deg[i] : 0;
    if (i < N) dinv[i] = (d > 0) ? rsqrtf((float)d) : 0.0f;
    s[threadIdx.x] = d;
    __syncthreads();
    for (int off = 128; off > 0; off >>= 1) {
        if (threadIdx.x < off) s[threadIdx.x] += s[threadIdx.x + off];
        __syncthreads();
    }
    if (threadIdx.x == 0) bsum[blockIdx.x] = s[0];
}

// ---------------- merged: rowStart (blocks < nB) | x convert (blocks >= nB) ----------------
__global__ void k_rs_cvt(const int* __restrict__ deg, const int* __restrict__ bsum,
                         int* __restrict__ rowStart,
                         const float4* __restrict__ X, const float* __restrict__ dinv,
                         uint2* __restrict__ Xb, uint* __restrict__ Xsb,
                         int N, int nB, int n4) {
    if ((int)blockIdx.x < nB) {
        __shared__ int s[256];
        int v = ((int)threadIdx.x < nB) ? bsum[threadIdx.x] : 0;
        s[threadIdx.x] = v;
        __syncthreads();
        for (int off = 1; off < 256; off <<= 1) {
            int t = (threadIdx.x >= off) ? s[threadIdx.x - off] : 0;
            __syncthreads();
            s[threadIdx.x] += t;
            __syncthreads();
        }
        const int base = (blockIdx.x == 0) ? 0 : s[blockIdx.x - 1];
        __syncthreads();
        int i = blockIdx.x * 256 + threadIdx.x;
        int d = (i < N) ? deg[i] : 0;
        s[threadIdx.x] = d;
        __syncthreads();
        for (int off = 1; off < 256; off <<= 1) {
            int t = (threadIdx.x >= off) ? s[threadIdx.x - off] : 0;
            __syncthreads();
            s[threadIdx.x] += t;
            __syncthreads();
        }
        if (i < N) {
            int incl = s[threadIdx.x];
            rowStart[i] = base + incl - d;
            if (i == N - 1) rowStart[N] = base + incl;
        }
    } else {
        int i = ((int)blockIdx.x - nB) * 256 + threadIdx.x;
        if (i >= n4) return;
        float4 v = X[i];
        float s = dinv[i >> 5];
        Xb[i]  = make_uint2(pk(v.x, v.y), pk(v.z, v.w));
        Xsb[i] = pk_fp8x4(v.x * s, v.y * s, v.z * s, v.w * s);
    }
}

// ---------------- CSR fill: pure scatter, no atomics ----------------
__global__ void k_fill(const int* __restrict__ row, const int* __restrict__ col,
                       const int* __restrict__ rowStart, const int* __restrict__ pos,
                       int* __restrict__ csr, int E) {
    int e = blockIdx.x * blockDim.x + threadIdx.x;
    if (e < E) csr[rowStart[row[e]] + pos[e]] = col[e];
}

// ---------------- SpMM (fp8 gather): Ob[i] = bf16( -dinv[i] * sum_j Xs[j] ) ----------------
// 32 lanes/row, lane owns uint = 4 fp8 ch (128B/neighbor), 2 rows/wave, unroll x4.
__global__ __launch_bounds__(256) void k_spmm(const uint* __restrict__ Xs,
                                              const float* __restrict__ dinv,
                                              const int* __restrict__ rowStart,
                                              const int* __restrict__ csr,
                                              uint2* __restrict__ Ob, int N) {
    int r = (int)((blockIdx.x * 256 + threadIdx.x) >> 5);
    int l = threadIdx.x & 31;
    if (r >= N) return;
    int s = rowStart[r], e = rowStart[r + 1];
    const uint* X = Xs + l;
    f32x2 a01 = {0.f, 0.f}, a23 = {0.f, 0.f};
    int k = s;
    for (; k + 4 <= e; k += 4) {
        int j0 = csr[k + 0], j1 = csr[k + 1], j2 = csr[k + 2], j3 = csr[k + 3];
        uint v0 = X[(size_t)j0 * 32];
        uint v1 = X[(size_t)j1 * 32];
        uint v2 = X[(size_t)j2 * 32];
        uint v3 = X[(size_t)j3 * 32];
        fp8x4_acc(v0, a01, a23);
        fp8x4_acc(v1, a01, a23);
        fp8x4_acc(v2, a01, a23);
        fp8x4_acc(v3, a01, a23);
    }
    for (; k < e; ++k) {
        uint v = X[(size_t)csr[k] * 32];
        fp8x4_acc(v, a01, a23);
    }
    float sc = -dinv[r];
    Ob[(size_t)r * 32 + l] = make_uint2(pk(a01[0] * sc, a01[1] * sc),
                                        pk(a23[0] * sc, a23[1] * sc));
}

// ---------------- MFMA GEMM: out = epi( [A1|A2] @ Wt^T + bias ) ----------------
// Tile 64 rows x 128 cols, 256 threads (4 waves, each 32x64). Grid 625.
__global__ __launch_bounds__(256) void k_gemm_mfma(const uint* __restrict__ A1,
                                                   const uint* __restrict__ A2,
                                                   const uint* __restrict__ Wt,
                                                   const float* __restrict__ bias,
                                                   const float* __restrict__ xres,
                                                   const float* __restrict__ dinv,
                                                   void* __restrict__ outp,
                                                   uchar* __restrict__ outs,
                                                   int N, int mode) {
    __shared__ uint AsU[2][64 * 20];
    __shared__ uint WsU[2][128 * 20];

    const int tid = threadIdx.x;
    const int lane = tid & 63;
    const int wid = tid >> 6;       // 0..3
    const int wr = wid >> 1;        // 0..1
    const int wc = wid & 1;         // 0..1
    const int row0 = blockIdx.x * 64;
    const int l16 = lane & 15;
    const int lk = lane >> 4;       // 0..3

    f32x4 acc[2][4];
    #pragma unroll
    for (int m = 0; m < 2; m++)
        #pragma unroll
        for (int n = 0; n < 4; n++)
            acc[m][n] = (f32x4){0.f, 0.f, 0.f, 0.f};

    const int sra = tid >> 2;       // 0..63 A-row
    const int sca = tid & 3;
    const uint4* A1p = (const uint4*)A1;
    const uint4* A2p = (const uint4*)A2;
    const uint4* Wtp = (const uint4*)Wt;
    const int arow = min(row0 + sra, N - 1);

    uint4 ga, gw0, gw1;
    ga  = A1p[(size_t)arow * 16 + sca];
    {
        int idx0 = tid, idx1 = tid + 256;
        gw0 = Wtp[(size_t)(idx0 >> 2) * 32 + (idx0 & 3)];
        gw1 = Wtp[(size_t)(idx1 >> 2) * 32 + (idx1 & 3)];
        *(uint4*)&AsU[0][sra * 20 + sca * 4] = ga;
        *(uint4*)&WsU[0][(idx0 >> 2) * 20 + (idx0 & 3) * 4] = gw0;
        *(uint4*)&WsU[0][(idx1 >> 2) * 20 + (idx1 & 3) * 4] = gw1;
    }
    __syncthreads();

    for (int t = 0; t < 8; ++t) {
        const int cur = t & 1;
        if (t < 7) {
            const int k0 = (t + 1) * 32;
            const uint4* Ap = (k0 < 128) ? A1p : A2p;
            const int kk = k0 & 127;
            ga  = Ap[(size_t)arow * 16 + (kk >> 3) + sca];
            int idx0 = tid, idx1 = tid + 256;
            gw0 = Wtp[(size_t)(idx0 >> 2) * 32 + (k0 >> 3) + (idx0 & 3)];
            gw1 = Wtp[(size_t)(idx1 >> 2) * 32 + (k0 >> 3) + (idx1 & 3)];
        }

        bf16x8 bfr[4];
        #pragma unroll
        for (int n = 0; n < 4; n++) {
            int col = wc * 64 + n * 16 + l16;
            bfr[n] = *(const bf16x8*)&WsU[cur][col * 20 + lk * 4];
        }
        #pragma unroll
        for (int m = 0; m < 2; m++) {
            int row = wr * 32 + m * 16 + l16;
            bf16x8 afr = *(const bf16x8*)&AsU[cur][row * 20 + lk * 4];
            #pragma unroll
            for (int n = 0; n < 4; n++)
                acc[m][n] = __builtin_amdgcn_mfma_f32_16x16x32_bf16(afr, bfr[n], acc[m][n], 0, 0, 0);
        }

        if (t < 7) {
            int idx0 = tid, idx1 = tid + 256;
            *(uint4*)&AsU[cur ^ 1][sra * 20 + sca * 4] = ga;
            *(uint4*)&WsU[cur ^ 1][(idx0 >> 2) * 20 + (idx0 & 3) * 4] = gw0;
            *(uint4*)&WsU[cur ^ 1][(idx1 >> 2) * 20 + (idx1 & 3) * 4] = gw1;
            __syncthreads();
        }
    }

    if (mode == 0) {
        ushort* O = (ushort*)outp;
        #pragma unroll
        for (int m = 0; m < 2; m++) {
            #pragma unroll
            for (int r = 0; r < 4; r++) {
                int rg = row0 + wr * 32 + m * 16 + lk * 4 + r;
                if (rg >= N) continue;
                float sc = dinv[rg];
                #pragma unroll
                for (int n = 0; n < 4; n++) {
                    const int col = wc * 64 + n * 16 + l16;
                    float v = fmaxf(acc[m][n][r] + bias[col], 0.f);
                    O[(size_t)rg * 128 + col] = f2bf(v);
                    outs[(size_t)rg * 128 + col] = f2fp8(v * sc);
                }
            }
        }
    } else {
        float* O = (float*)outp;
        #pragma unroll
        for (int m = 0; m < 2; m++) {
            #pragma unroll
            for (int r = 0; r < 4; r++) {
                int rg = row0 + wr * 32 + m * 16 + lk * 4 + r;
                if (rg >= N) continue;
                #pragma unroll
                for (int n = 0; n < 4; n++) {
                    const int col = wc * 64 + n * 16 + l16;
                    float v = fmaxf(acc[m][n][r] + bias[col], 0.f);
                    O[(size_t)rg * 128 + col] = 0.5f * (v + xres[(size_t)rg * 128 + col]);
                }
            }
        }
    }
}

extern "C" void kernel_launch(void* const* d_in, const int* in_sizes, int n_in,
                              void* d_out, int out_size, void* d_ws, size_t ws_size,
                              hipStream_t stream) {
    const float* x   = (const float*)d_in[0];
    const int*   ei  = (const int*)d_in[1];
    const float* W00 = (const float*)d_in[2];
    const float* W01 = (const float*)d_in[3];
    const float* b0  = (const float*)d_in[4];
    const float* W10 = (const float*)d_in[5];
    const float* W11 = (const float*)d_in[6];
    const float* b1  = (const float*)d_in[7];
    float* out = (float*)d_out;

    const int N = in_sizes[0] / CH;   // 40000
    const int E = in_sizes[1] / 2;    // 640000
    const int* row = ei;
    const int* col = ei + E;

    char* ws = (char*)d_ws;
    size_t off = 0;
    auto alloc = [&](size_t bytes) -> void* {
        void* p = ws + off;
        off += (bytes + 255) & ~(size_t)255;
        return p;
    };
    int*   deg      = (int*)alloc((size_t)N * 4);
    float* dinv     = (float*)alloc((size_t)N * 4);
    int*   rowStart = (int*)alloc((size_t)(N + 1) * 4);
    int*   pos      = (int*)alloc((size_t)E * 4);
    int*   bsum     = (int*)alloc(4096);
    int*   csr      = (int*)alloc((size_t)E * 4);
    uint*  xb       = (uint*)alloc((size_t)N * 64 * 4);   // bf16 GEMM operand
    uint*  xsb      = (uint*)alloc((size_t)N * 32 * 4);   // fp8 gather operand
    uint*  Lb       = (uint*)alloc((size_t)N * 64 * 4);   // bf16 L~ result
    uint*  yb       = (uint*)alloc((size_t)N * 64 * 4);   // bf16 GEMM operand
    uchar* ysb      = (uchar*)alloc((size_t)N * 128);     // fp8 gather operand
    uint*  Wt0      = (uint*)alloc(128 * 128 * 4);
    uint*  Wt1      = (uint*)alloc(128 * 128 * 4);

    const int nB = (N + 255) / 256;       // 157 <= 256
    const int n4 = N * 32;                // float4 elements in x
    const int cvtB = (n4 + 255) / 256;    // 5000

    k_prolog<<<128 + nB, 256, 0, stream>>>(W00, W01, W10, W11, Wt0, Wt1, deg, N);
    k_deg<<<(E + 255) / 256, 256, 0, stream>>>(row, deg, pos, E);
    k_dinv_bsum<<<nB, 256, 0, stream>>>(deg, dinv, bsum, N);
    k_rs_cvt<<<nB + cvtB, 256, 0, stream>>>(deg, bsum, rowStart,
                                            (const float4*)x, dinv,
                                            (uint2*)xb, xsb, N, nB, n4);
    k_fill<<<(E + 255) / 256, 256, 0, stream>>>(row, col, rowStart, pos, csr, E);

    const int gemmBlocks = (N + 63) / 64;          // 625
    const int spmmBlocks = (N * 32 + 255) / 256;   // 5000

    // layer 1
    k_spmm<<<spmmBlocks, 256, 0, stream>>>(xsb, dinv, rowStart, csr, (uint2*)Lb, N);
    k_gemm_mfma<<<gemmBlocks, 256, 0, stream>>>(xb, Lb, Wt0, b0, nullptr, dinv,
                                                (void*)yb, ysb, N, 0);

    // layer 2
    k_spmm<<<spmmBlocks, 256, 0, stream>>>((const uint*)ysb, dinv, rowStart, csr,
                                           (uint2*)Lb, N);
    k_gemm_mfma<<<gemmBlocks, 256, 0, stream>>>(yb, Lb, Wt1, b1, x, dinv,
                                                (void*)out, nullptr, N, 1);
}